// Round 2
// baseline (5288.511 us; speedup 1.0000x reference)
//
#include <hip/hip_runtime.h>

typedef __bf16 bf16_t;
typedef __bf16 bf16x8 __attribute__((ext_vector_type(8)));
typedef __bf16 bf16x4 __attribute__((ext_vector_type(4)));
typedef __bf16 bf16x2 __attribute__((ext_vector_type(2)));
typedef float f32x16 __attribute__((ext_vector_type(16)));

// Problem dims: B=32, S=512, D=512, H=1024, 4H=4096
// ws layout (bytes)
#define SZ_XBF    (16384ull*512*2)      // x bf16, rows permuted to t*32+b
#define SZ_WIH    (4096ull*512*2)
#define SZ_WHH    (4096ull*1024*2)
#define SZ_XPROJ  (16384ull*4096*2)     // [t*32+b][4096] bf16
#define SZ_HTR    (513ull*32*1024*2)    // h trace bf16, slot 0 = h0
#define OFF_XBF   (0ull)
#define OFF_WIH   (OFF_XBF + SZ_XBF)
#define OFF_WHH   (OFF_WIH + SZ_WIH)
#define OFF_XPROJ (OFF_WHH + SZ_WHH)
#define OFF_HTR   (OFF_XPROJ + SZ_XPROJ)
#define OFF_FLAGS (OFF_HTR + SZ_HTR)    // 64 contiguous ints (256B)

// h trace layout (slab-contiguous per producer):
//   HTR[t*32768 + slab*512 + b*16 + col]  encodes h_t[b][slab*16 + col]
// Each (t, slab) region is 1KB contiguous (1KB-aligned, no line spans
// producers), written by exactly one WG and read only after that WG's flag.
// Slab granularity == MFMA k-step granularity: slab (khalf*32+s) is exactly
// the A-fragment of MFMA s for the wave with that khalf -> per-producer
// pipelined consumption with static register indices.

// ---------------------------------------------------------------------------
// Kernel 1: convert inputs to bf16 (x permuted), init h-trace slot 0, zero flags
// ---------------------------------------------------------------------------
__global__ __launch_bounds__(256) void convert_pack(
    const float* __restrict__ x, const float* __restrict__ h0,
    const float* __restrict__ Wih, const float* __restrict__ Whh,
    bf16_t* __restrict__ xbf, bf16_t* __restrict__ wihbf,
    bf16_t* __restrict__ whhbf, bf16_t* __restrict__ htr,
    int* __restrict__ flags)
{
  long long v = (long long)blockIdx.x * 256 + threadIdx.x;
  if (v < 2097152LL) {                       // x: 8388608 floats, 4 per thread
    long long fi = v * 4;
    int b = (int)(fi >> 18);                 // 512*512 = 2^18
    int rem = (int)(fi & 0x3FFFF);
    int s = rem >> 9, d = rem & 511;
    float4 f = *(const float4*)(x + fi);
    bf16x4 o; o.x = (bf16_t)f.x; o.y = (bf16_t)f.y; o.z = (bf16_t)f.z; o.w = (bf16_t)f.w;
    *(bf16x4*)(xbf + ((long long)(s*32 + b)*512 + d)) = o;
  } else if (v < 2621440LL) {                // W_ih: 2097152 floats
    long long fi = (v - 2097152LL) * 4;
    float4 f = *(const float4*)(Wih + fi);
    bf16x4 o; o.x = (bf16_t)f.x; o.y = (bf16_t)f.y; o.z = (bf16_t)f.z; o.w = (bf16_t)f.w;
    *(bf16x4*)(wihbf + fi) = o;
  } else if (v < 3670016LL) {                // W_hh: 4194304 floats
    long long fi = (v - 2621440LL) * 4;
    float4 f = *(const float4*)(Whh + fi);
    bf16x4 o; o.x = (bf16_t)f.x; o.y = (bf16_t)f.y; o.z = (bf16_t)f.z; o.w = (bf16_t)f.w;
    *(bf16x4*)(whhbf + fi) = o;
  } else if (v < 3678208LL) {                // h0: 32768 floats -> htr slot 0 (slab layout)
    long long fi = (v - 3670016LL) * 4;
    int b = (int)(fi >> 10), c = (int)(fi & 1023);
    float4 f = *(const float4*)(h0 + fi);
    bf16x4 o; o.x = (bf16_t)f.x; o.y = (bf16_t)f.y; o.z = (bf16_t)f.z; o.w = (bf16_t)f.w;
    *(bf16x4*)(htr + (long long)(c >> 4) * 512 + b * 16 + (c & 15)) = o;
  } else if (v < 3678224LL) {                // flags: 64 ints -> 0
    int i = (int)(v - 3678208LL) * 4;
    *(int4*)(flags + i) = make_int4(0, 0, 0, 0);
  }
}

// ---------------------------------------------------------------------------
// Kernel 2: x_proj = X(bf16, rows t*32+b) @ W_ih^T + b_ih + b_hh  -> bf16
// ---------------------------------------------------------------------------
__global__ __launch_bounds__(256) void xproj_gemm(
    const bf16_t* __restrict__ Xb, const bf16_t* __restrict__ Wb,
    const float* __restrict__ bih, const float* __restrict__ bhh,
    bf16_t* __restrict__ XP)
{
  __shared__ bf16_t As[128*64];
  __shared__ bf16_t Bs[128*64];
  const int tid = threadIdx.x;
  const int lane = tid & 63, wave = tid >> 6;
  const int mhalf = wave & 1, nhalf = wave >> 1;
  const int l31 = lane & 31, khi = lane >> 5;
  const int m0 = blockIdx.x * 128, n0 = blockIdx.y * 128;

  f32x16 acc[2][2] = {};

  for (int kb = 0; kb < 8; ++kb) {
    const int k0 = kb * 64;
    __syncthreads();
#pragma unroll
    for (int j = 0; j < 4; ++j) {
      int cid = j * 256 + tid;
      int r = cid >> 3, bs = cid & 7;
      int bb = bs ^ (r & 7);
      *(bf16x8*)(As + cid * 8) = *(const bf16x8*)(Xb + (long long)(m0 + r) * 512 + k0 + bb * 8);
      *(bf16x8*)(Bs + cid * 8) = *(const bf16x8*)(Wb + (long long)(n0 + r) * 512 + k0 + bb * 8);
    }
    __syncthreads();
#pragma unroll
    for (int ks = 0; ks < 4; ++ks) {
      int blk = ks * 2 + khi;
      bf16x8 af[2], bfr[2];
#pragma unroll
      for (int mt = 0; mt < 2; ++mt) {
        int r = mhalf * 64 + mt * 32 + l31;
        af[mt] = *(const bf16x8*)(As + (r * 8 + (blk ^ (r & 7))) * 8);
      }
#pragma unroll
      for (int nt = 0; nt < 2; ++nt) {
        int r = nhalf * 64 + nt * 32 + l31;
        bfr[nt] = *(const bf16x8*)(Bs + (r * 8 + (blk ^ (r & 7))) * 8);
      }
#pragma unroll
      for (int mt = 0; mt < 2; ++mt)
#pragma unroll
        for (int nt = 0; nt < 2; ++nt)
          acc[mt][nt] = __builtin_amdgcn_mfma_f32_32x32x16_bf16(af[mt], bfr[nt], acc[mt][nt], 0, 0, 0);
    }
  }
#pragma unroll
  for (int nt = 0; nt < 2; ++nt) {
    int ng = n0 + nhalf * 64 + nt * 32 + l31;
    float bias = bih[ng] + bhh[ng];
#pragma unroll
    for (int mt = 0; mt < 2; ++mt) {
#pragma unroll
      for (int r = 0; r < 16; ++r) {
        int row = (r & 3) + 8 * (r >> 2) + 4 * khi;
        long long mg = m0 + mhalf * 64 + mt * 32 + row;   // = t*32 + b
        XP[mg * 4096 + ng] = (bf16_t)(acc[mt][nt][r] + bias);
      }
    }
  }
}

// ---------------------------------------------------------------------------
// Kernel 3: persistent LSTM recurrence, sc1-only cross-WG sync.
// 64 WGs x 256 threads; WG owns 16 h-cols (64 gate rows); W_hh slice in regs.
// NEW vs previous version:
//  - per-producer pipelined consumption: each wave polls the 32 flags of its
//    own K-half with one wave-wide flag load (ballot -> ready mask) and
//    consumes slabs IN ORDER as they become ready. Slabs already published
//    are loaded/MFMA'd while stragglers are still in flight, so the
//    max-of-64 wait overlaps the dot-product work. Static wreg[s] indices.
//  - post-wait __syncthreads removed (every wave polls for itself; the
//    publish-side barrier already orders gL writes vs prior-step reads).
//    2 barriers per step instead of 3.
// Ordering (unchanged): h stores -> s_waitcnt vmcnt(0) -> __syncthreads ->
// flag sc1 store. Consumer reads slab p of step t only after flags[p] >= t.
// ---------------------------------------------------------------------------
__device__ __forceinline__ float sigf(float x) { return 1.0f / (1.0f + __expf(-x)); }
__device__ __forceinline__ float tanhfast(float x) {
  float e = __expf(-2.0f * fabsf(x));
  float t = (1.0f - e) / (1.0f + e);
  return copysignf(t, x);
}

__global__ __launch_bounds__(256, 1) void lstm_rec(
    const bf16_t* __restrict__ Whh_b, const bf16_t* __restrict__ XP,
    const float* __restrict__ c0, float* __restrict__ OUT,
    bf16_t* __restrict__ HTR, int* flags)
{
  const int tid = threadIdx.x;
  const int lane = tid & 63, wave = tid >> 6;
  const int ntile = wave & 1, khalf = wave >> 1;   // 2 N-tiles x 2 K-halves
  const int wg = blockIdx.x;
  const int l31 = lane & 31, khi = lane >> 5;

  // --- preload W_hh fragments into registers (unchanged k mapping) ---
  const int nl = ntile * 32 + l31;                          // local gate col
  const int grow = (nl >> 4) * 1024 + wg * 16 + (nl & 15);  // W_hh row
  const int kbase = khalf * 512 + khi * 8;
  bf16x8 wreg[32];
#pragma unroll
  for (int s = 0; s < 32; ++s)
    wreg[s] = *(const bf16x8*)(Whh_b + (long long)grow * 1024 + kbase + s * 16);

  // A-fragment: slab (khalf*32+s), row l31, cols khi*8..+8
  //   addr = t*32768 + (khalf*32+s)*512 + l31*16 + khi*8
  const int aoff = khalf * 16384 + l31 * 16 + khi * 8;
  const int* fp = flags + khalf * 32 + l31;   // lanes 0..31 and 32..63 dup

  __shared__ float gL[2][32][65];   // [khalf][m][n_local], padded
  __shared__ float cS[32][18];      // c state fp32, padded
  const int m_e = tid >> 3;
  const int jp = (tid & 7) * 2;
  cS[m_e][jp]     = c0[m_e * 1024 + wg * 16 + jp];
  cS[m_e][jp + 1] = c0[m_e * 1024 + wg * 16 + jp + 1];
  __syncthreads();

  // prefetch xp for t=0
  float xp[4][2];
  {
    const bf16_t* xpb = XP + (long long)m_e * 4096 + wg * 16 + jp;
#pragma unroll
    for (int g = 0; g < 4; ++g) {
      bf16x2 v = *(const bf16x2*)(xpb + g * 1024);
      xp[g][0] = (float)v.x; xp[g][1] = (float)v.y;
    }
  }

  for (int t = 0; t < 512; ++t) {
    // gates partial = W_slice . h_t, consuming producer slabs as they land.
    // rdy bit p: producer (khalf*32+p) has published step t.
    const bf16_t* hb = HTR + (long long)t * 32768 + aoff;
    f32x16 acc0 = {}, acc1 = {};
    unsigned rdy = 0u;
#pragma unroll
    for (int s = 0; s < 32; ++s) {
      if (!((rdy >> s) & 1u)) {
        for (;;) {
          int f = __hip_atomic_load(fp, __ATOMIC_RELAXED, __HIP_MEMORY_SCOPE_AGENT);
          unsigned long long bal = __ballot(f >= t);
          rdy |= (unsigned)bal;                 // lanes 0..31 cover my 32 producers
          if ((rdy >> s) & 1u) break;
        }
      }
      bf16x8 a = *(const bf16x8*)(hb + s * 512);
      if (s < 16) acc0 = __builtin_amdgcn_mfma_f32_32x32x16_bf16(a, wreg[s], acc0, 0, 0, 0);
      else        acc1 = __builtin_amdgcn_mfma_f32_32x32x16_bf16(a, wreg[s], acc1, 0, 0, 0);
    }
#pragma unroll
    for (int r = 0; r < 16; ++r) {
      int mm = (r & 3) + 8 * (r >> 2) + 4 * khi;
      gL[khalf][mm][nl] = acc0[r] + acc1[r];
    }
    __syncthreads();   // barrier A: gL complete

    // elementwise LSTM cell for (m_e, jp..jp+1)
    float hv[2];
#pragma unroll
    for (int e = 0; e < 2; ++e) {
      int j = jp + e;
      float ir  = gL[0][m_e][j]      + gL[1][m_e][j]      + xp[0][e];
      float fr  = gL[0][m_e][16 + j] + gL[1][m_e][16 + j] + xp[1][e];
      float gr  = gL[0][m_e][32 + j] + gL[1][m_e][32 + j] + xp[2][e];
      float orr = gL[0][m_e][48 + j] + gL[1][m_e][48 + j] + xp[3][e];
      float iv = sigf(ir), fv = sigf(fr), gv = tanhfast(gr), ov = sigf(orr);
      float c = fv * cS[m_e][j] + iv * gv;
      cS[m_e][j] = c;
      hv[e] = ov * tanhfast(c);
    }
    // publish h (sc1 write-through to LLC) into this WG's contiguous slab;
    // 256 threads store 1KB fully coalesced (single-owner lines)
    {
      bf16x2 h2; h2.x = (bf16_t)hv[0]; h2.y = (bf16_t)hv[1];
      unsigned int u = __builtin_bit_cast(unsigned int, h2);
      unsigned int* dst = (unsigned int*)(HTR + (long long)(t + 1) * 32768 +
                                          (long long)wg * 512 + m_e * 16 + jp);
      __hip_atomic_store(dst, u, __ATOMIC_RELAXED, __HIP_MEMORY_SCOPE_AGENT);
    }
    asm volatile("s_waitcnt vmcnt(0)" ::: "memory");  // h stores are at LLC
    __syncthreads();                                  // barrier B: all stores done
    if (tid == 0)
      __hip_atomic_store(&flags[wg], t + 1, __ATOMIC_RELAXED,
                         __HIP_MEMORY_SCOPE_AGENT);

    // --- off the critical path: OUT store + next-step xp prefetch ---
    *(float2*)(OUT + ((long long)m_e * 512 + t) * 1024 + wg * 16 + jp) =
        make_float2(hv[0], hv[1]);
    if (t < 511) {
      const bf16_t* xpb = XP + ((long long)(t + 1) * 32 + m_e) * 4096 + wg * 16 + jp;
#pragma unroll
      for (int g = 0; g < 4; ++g) {
        bf16x2 v = *(const bf16x2*)(xpb + g * 1024);
        xp[g][0] = (float)v.x; xp[g][1] = (float)v.y;
      }
    }
  }
}

// ---------------------------------------------------------------------------
extern "C" void kernel_launch(void* const* d_in, const int* in_sizes, int n_in,
                              void* d_out, int out_size, void* d_ws, size_t ws_size,
                              hipStream_t stream)
{
  const float* x   = (const float*)d_in[0];
  const float* h0  = (const float*)d_in[1];
  const float* c0  = (const float*)d_in[2];
  const float* Wih = (const float*)d_in[3];
  const float* Whh = (const float*)d_in[4];
  const float* bih = (const float*)d_in[5];
  const float* bhh = (const float*)d_in[6];
  float* out = (float*)d_out;

  char* ws = (char*)d_ws;
  bf16_t* xbf   = (bf16_t*)(ws + OFF_XBF);
  bf16_t* wihbf = (bf16_t*)(ws + OFF_WIH);
  bf16_t* whhbf = (bf16_t*)(ws + OFF_WHH);
  bf16_t* xproj = (bf16_t*)(ws + OFF_XPROJ);
  bf16_t* htr   = (bf16_t*)(ws + OFF_HTR);
  int* flags    = (int*)(ws + OFF_FLAGS);

  convert_pack<<<14369, 256, 0, stream>>>(x, h0, Wih, Whh, xbf, wihbf, whhbf, htr, flags);
  xproj_gemm<<<dim3(128, 32), 256, 0, stream>>>(xbf, wihbf, bih, bhh, xproj);
  lstm_rec<<<64, 256, 0, stream>>>(whhbf, xproj, c0, out, htr, flags);
}

// Round 3
// 1786.459 us; speedup vs baseline: 2.9603x; 2.9603x over previous
//
#include <hip/hip_runtime.h>

typedef __bf16 bf16_t;
typedef __bf16 bf16x8 __attribute__((ext_vector_type(8)));
typedef __bf16 bf16x4 __attribute__((ext_vector_type(4)));
typedef __bf16 bf16x2 __attribute__((ext_vector_type(2)));
typedef float f32x16 __attribute__((ext_vector_type(16)));
typedef int i32x4 __attribute__((ext_vector_type(4)));

// Problem dims: B=32, S=512, D=512, H=1024, 4H=4096
// ws layout (bytes)
#define SZ_XBF    (16384ull*512*2)      // x bf16, rows permuted to t*32+b
#define SZ_WIH    (4096ull*512*2)
#define SZ_WHH    (4096ull*1024*2)
#define SZ_XPROJ  (16384ull*4096*2)     // [t*32+b][4096] bf16
#define SZ_HTR    (513ull*32*1024*2)    // h trace bf16, slot 0 = h0
#define OFF_XBF   (0ull)
#define OFF_WIH   (OFF_XBF + SZ_XBF)
#define OFF_WHH   (OFF_WIH + SZ_WIH)
#define OFF_XPROJ (OFF_WHH + SZ_WHH)
#define OFF_HTR   (OFF_XPROJ + SZ_XPROJ)

// h trace layout (slab-contiguous per producer):
//   HTR[t*32768 + slab*512 + b*16 + col]  encodes h_t[b][slab*16 + col]
// Each (t, slab) region is 1KB contiguous, written dword-wise by exactly one
// WG. Slots 1..512 are pre-filled with canary 0xFFFFFFFF (bf16 -NaN pair,
// impossible for real h = o*tanh(c), always finite). Consumers bulk-load all
// 32 slabs with cache-bypassing loads and retry until no canary dword remains:
// the DATA is the flag -> no flag store, no producer vmcnt ack, no flag-poll
// RTT. Per-dword store atomicity makes this sound with zero fences.

// ---------------------------------------------------------------------------
// Kernel 1: convert inputs to bf16 (x permuted), init h-trace slot 0,
//           canary-fill h-trace slots 1..512
// ---------------------------------------------------------------------------
__global__ __launch_bounds__(256) void convert_pack(
    const float* __restrict__ x, const float* __restrict__ h0,
    const float* __restrict__ Wih, const float* __restrict__ Whh,
    bf16_t* __restrict__ xbf, bf16_t* __restrict__ wihbf,
    bf16_t* __restrict__ whhbf, bf16_t* __restrict__ htr)
{
  long long v = (long long)blockIdx.x * 256 + threadIdx.x;
  if (v < 2097152LL) {                       // x: 8388608 floats, 4 per thread
    long long fi = v * 4;
    int b = (int)(fi >> 18);                 // 512*512 = 2^18
    int rem = (int)(fi & 0x3FFFF);
    int s = rem >> 9, d = rem & 511;
    float4 f = *(const float4*)(x + fi);
    bf16x4 o; o.x = (bf16_t)f.x; o.y = (bf16_t)f.y; o.z = (bf16_t)f.z; o.w = (bf16_t)f.w;
    *(bf16x4*)(xbf + ((long long)(s*32 + b)*512 + d)) = o;
  } else if (v < 2621440LL) {                // W_ih: 2097152 floats
    long long fi = (v - 2097152LL) * 4;
    float4 f = *(const float4*)(Wih + fi);
    bf16x4 o; o.x = (bf16_t)f.x; o.y = (bf16_t)f.y; o.z = (bf16_t)f.z; o.w = (bf16_t)f.w;
    *(bf16x4*)(wihbf + fi) = o;
  } else if (v < 3670016LL) {                // W_hh: 4194304 floats
    long long fi = (v - 2621440LL) * 4;
    float4 f = *(const float4*)(Whh + fi);
    bf16x4 o; o.x = (bf16_t)f.x; o.y = (bf16_t)f.y; o.z = (bf16_t)f.z; o.w = (bf16_t)f.w;
    *(bf16x4*)(whhbf + fi) = o;
  } else if (v < 3678208LL) {                // h0: 32768 floats -> htr slot 0 (slab layout)
    long long fi = (v - 3670016LL) * 4;
    int b = (int)(fi >> 10), c = (int)(fi & 1023);
    float4 f = *(const float4*)(h0 + fi);
    bf16x4 o; o.x = (bf16_t)f.x; o.y = (bf16_t)f.y; o.z = (bf16_t)f.z; o.w = (bf16_t)f.w;
    *(bf16x4*)(htr + (long long)(c >> 4) * 512 + b * 16 + (c & 15)) = o;
  } else if (v < 5775360LL) {                // canary fill slots 1..512 (16.78M elems)
    long long idx = v - 3678208LL;           // 2097152 threads * 8 elems
    *(int4*)(htr + 32768LL + idx * 8) = make_int4(-1, -1, -1, -1);
  }
}

// ---------------------------------------------------------------------------
// Kernel 2: x_proj = X(bf16, rows t*32+b) @ W_ih^T + b_ih + b_hh  -> bf16
// ---------------------------------------------------------------------------
__global__ __launch_bounds__(256) void xproj_gemm(
    const bf16_t* __restrict__ Xb, const bf16_t* __restrict__ Wb,
    const float* __restrict__ bih, const float* __restrict__ bhh,
    bf16_t* __restrict__ XP)
{
  __shared__ bf16_t As[128*64];
  __shared__ bf16_t Bs[128*64];
  const int tid = threadIdx.x;
  const int lane = tid & 63, wave = tid >> 6;
  const int mhalf = wave & 1, nhalf = wave >> 1;
  const int l31 = lane & 31, khi = lane >> 5;
  const int m0 = blockIdx.x * 128, n0 = blockIdx.y * 128;

  f32x16 acc[2][2] = {};

  for (int kb = 0; kb < 8; ++kb) {
    const int k0 = kb * 64;
    __syncthreads();
#pragma unroll
    for (int j = 0; j < 4; ++j) {
      int cid = j * 256 + tid;
      int r = cid >> 3, bs = cid & 7;
      int bb = bs ^ (r & 7);
      *(bf16x8*)(As + cid * 8) = *(const bf16x8*)(Xb + (long long)(m0 + r) * 512 + k0 + bb * 8);
      *(bf16x8*)(Bs + cid * 8) = *(const bf16x8*)(Wb + (long long)(n0 + r) * 512 + k0 + bb * 8);
    }
    __syncthreads();
#pragma unroll
    for (int ks = 0; ks < 4; ++ks) {
      int blk = ks * 2 + khi;
      bf16x8 af[2], bfr[2];
#pragma unroll
      for (int mt = 0; mt < 2; ++mt) {
        int r = mhalf * 64 + mt * 32 + l31;
        af[mt] = *(const bf16x8*)(As + (r * 8 + (blk ^ (r & 7))) * 8);
      }
#pragma unroll
      for (int nt = 0; nt < 2; ++nt) {
        int r = nhalf * 64 + nt * 32 + l31;
        bfr[nt] = *(const bf16x8*)(Bs + (r * 8 + (blk ^ (r & 7))) * 8);
      }
#pragma unroll
      for (int mt = 0; mt < 2; ++mt)
#pragma unroll
        for (int nt = 0; nt < 2; ++nt)
          acc[mt][nt] = __builtin_amdgcn_mfma_f32_32x32x16_bf16(af[mt], bfr[nt], acc[mt][nt], 0, 0, 0);
    }
  }
#pragma unroll
  for (int nt = 0; nt < 2; ++nt) {
    int ng = n0 + nhalf * 64 + nt * 32 + l31;
    float bias = bih[ng] + bhh[ng];
#pragma unroll
    for (int mt = 0; mt < 2; ++mt) {
#pragma unroll
      for (int r = 0; r < 16; ++r) {
        int row = (r & 3) + 8 * (r >> 2) + 4 * khi;
        long long mg = m0 + mhalf * 64 + mt * 32 + row;   // = t*32 + b
        XP[mg * 4096 + ng] = (bf16_t)(acc[mt][nt][r] + bias);
      }
    }
  }
}

// ---------------------------------------------------------------------------
// Kernel 3: persistent LSTM recurrence, canary-validated data-poll sync.
// 64 WGs x 256 threads; WG owns 16 h-cols (64 gate rows); W_hh slice in regs.
//  - consumers bulk-load their 32 slabs (sc0 sc1 = bypass L1+L2, read LLC)
//    and retry until no dword is canary: detection == data arrival (1 RTT).
//  - no flags, no producer vmcnt ack, no barrier B: h store is fire-and-forget.
//  - gL double-buffered by t-parity -> ONE barrier per step.
//  - c state in registers (thread-private).
//  - OUT store deferred one step so its write-ack is off the vmcnt(0) path.
// ---------------------------------------------------------------------------
__device__ __forceinline__ float sigf(float x) { return 1.0f / (1.0f + __expf(-x)); }
__device__ __forceinline__ float tanhfast(float x) {
  float e = __expf(-2.0f * fabsf(x));
  float t = (1.0f - e) / (1.0f + e);
  return copysignf(t, x);
}
__device__ __forceinline__ unsigned umax2(unsigned a, unsigned b) { return a > b ? a : b; }
__device__ __forceinline__ unsigned umax4(i32x4 v) {
  return umax2(umax2((unsigned)v[0], (unsigned)v[1]),
               umax2((unsigned)v[2], (unsigned)v[3]));
}

#define LD16(dst, ptr, OFF) \
  asm volatile("global_load_dwordx4 %0, %1, off offset:" OFF " sc0 sc1" \
               : "=v"(dst) : "v"(ptr) : "memory")

__global__ __launch_bounds__(256, 1) void lstm_rec(
    const bf16_t* __restrict__ Whh_b, const bf16_t* __restrict__ XP,
    const float* __restrict__ c0, float* __restrict__ OUT,
    bf16_t* __restrict__ HTR)
{
  const int tid = threadIdx.x;
  const int lane = tid & 63, wave = tid >> 6;
  const int ntile = wave & 1, khalf = wave >> 1;   // 2 N-tiles x 2 K-halves
  const int wg = blockIdx.x;
  const int l31 = lane & 31, khi = lane >> 5;

  // --- preload W_hh fragments into registers (unchanged k mapping) ---
  const int nl = ntile * 32 + l31;                          // local gate col
  const int grow = (nl >> 4) * 1024 + wg * 16 + (nl & 15);  // W_hh row
  const int kbase = khalf * 512 + khi * 8;
  bf16x8 wreg[32];
#pragma unroll
  for (int s = 0; s < 32; ++s)
    wreg[s] = *(const bf16x8*)(Whh_b + (long long)grow * 1024 + kbase + s * 16);

  // A-fragment byte base: slab (khalf*32+s), row l31, cols khi*8..+8
  //   byte = t*65536 + khalf*32768 + s*1024 + l31*32 + khi*16
  const char* abase = (const char*)HTR + khalf * 32768 + l31 * 32 + khi * 16;

  __shared__ float gLb[2][2][32][65];   // [t parity][khalf][m][n_local], padded
  const int m_e = tid >> 3;
  const int jp = (tid & 7) * 2;
  float cr0 = c0[m_e * 1024 + wg * 16 + jp];
  float cr1 = c0[m_e * 1024 + wg * 16 + jp + 1];

  // prefetch xp for t=0
  float xp[4][2];
  {
    const bf16_t* xpb = XP + (long long)m_e * 4096 + wg * 16 + jp;
#pragma unroll
    for (int g = 0; g < 4; ++g) {
      bf16x2 v = *(const bf16x2*)(xpb + g * 1024);
      xp[g][0] = (float)v.x; xp[g][1] = (float)v.y;
    }
  }

  float po0 = 0.0f, po1 = 0.0f;   // deferred OUT values (step t-1)

  for (int t = 0; t < 512; ++t) {
    // ---- bulk-load + canary-validate the 32 slabs of my K-half ----
    const char* p0 = abase + ((long long)t << 16);
    const char* p1 = p0 + 4096;  const char* p2 = p0 + 8192;
    const char* p3 = p0 + 12288; const char* p4 = p0 + 16384;
    const char* p5 = p0 + 20480; const char* p6 = p0 + 24576;
    const char* p7 = p0 + 28672;
    i32x4 a[32];
    for (;;) {
      LD16(a[0],  p0, "0"); LD16(a[1],  p0, "1024"); LD16(a[2],  p0, "2048"); LD16(a[3],  p0, "3072");
      LD16(a[4],  p1, "0"); LD16(a[5],  p1, "1024"); LD16(a[6],  p1, "2048"); LD16(a[7],  p1, "3072");
      LD16(a[8],  p2, "0"); LD16(a[9],  p2, "1024"); LD16(a[10], p2, "2048"); LD16(a[11], p2, "3072");
      LD16(a[12], p3, "0"); LD16(a[13], p3, "1024"); LD16(a[14], p3, "2048"); LD16(a[15], p3, "3072");
      LD16(a[16], p4, "0"); LD16(a[17], p4, "1024"); LD16(a[18], p4, "2048"); LD16(a[19], p4, "3072");
      LD16(a[20], p5, "0"); LD16(a[21], p5, "1024"); LD16(a[22], p5, "2048"); LD16(a[23], p5, "3072");
      LD16(a[24], p6, "0"); LD16(a[25], p6, "1024"); LD16(a[26], p6, "2048"); LD16(a[27], p6, "3072");
      LD16(a[28], p7, "0"); LD16(a[29], p7, "1024"); LD16(a[30], p7, "2048"); LD16(a[31], p7, "3072");
      asm volatile("s_waitcnt vmcnt(0)" ::: "memory");
      __builtin_amdgcn_sched_barrier(0);
      unsigned mA = 0, mB = 0, mC = 0, mD = 0;
#pragma unroll
      for (int s = 0; s < 32; s += 4) {
        mA = umax2(mA, umax4(a[s]));
        mB = umax2(mB, umax4(a[s + 1]));
        mC = umax2(mC, umax4(a[s + 2]));
        mD = umax2(mD, umax4(a[s + 3]));
      }
      unsigned mx = umax2(umax2(mA, mB), umax2(mC, mD));
      if (!__any((int)(mx == 0xFFFFFFFFu))) break;
    }

    // ---- deferred OUT store for step t-1 (ack off the critical wait) ----
    if (t > 0)
      *(float2*)(OUT + ((long long)m_e * 512 + (t - 1)) * 1024 + wg * 16 + jp) =
          make_float2(po0, po1);

    // ---- gates partial = W_slice . h_t ----
    f32x16 acc0 = {}, acc1 = {};
#pragma unroll
    for (int s = 0; s < 16; ++s)
      acc0 = __builtin_amdgcn_mfma_f32_32x32x16_bf16(
          __builtin_bit_cast(bf16x8, a[s]), wreg[s], acc0, 0, 0, 0);
#pragma unroll
    for (int s = 16; s < 32; ++s)
      acc1 = __builtin_amdgcn_mfma_f32_32x32x16_bf16(
          __builtin_bit_cast(bf16x8, a[s]), wreg[s], acc1, 0, 0, 0);

    float (*gp)[32][65] = gLb[t & 1];
#pragma unroll
    for (int r = 0; r < 16; ++r) {
      int mm = (r & 3) + 8 * (r >> 2) + 4 * khi;
      gp[khalf][mm][nl] = acc0[r] + acc1[r];
    }
    __syncthreads();   // single barrier per step (gL parity-double-buffered)

    // ---- elementwise LSTM cell for (m_e, jp..jp+1), c in registers ----
    float hv[2];
    {
      float ir  = gp[0][m_e][jp]      + gp[1][m_e][jp]      + xp[0][0];
      float fr  = gp[0][m_e][16 + jp] + gp[1][m_e][16 + jp] + xp[1][0];
      float gr  = gp[0][m_e][32 + jp] + gp[1][m_e][32 + jp] + xp[2][0];
      float orr = gp[0][m_e][48 + jp] + gp[1][m_e][48 + jp] + xp[3][0];
      float c = sigf(fr) * cr0 + sigf(ir) * tanhfast(gr);
      cr0 = c;
      hv[0] = sigf(orr) * tanhfast(c);
    }
    {
      int j = jp + 1;
      float ir  = gp[0][m_e][j]      + gp[1][m_e][j]      + xp[0][1];
      float fr  = gp[0][m_e][16 + j] + gp[1][m_e][16 + j] + xp[1][1];
      float gr  = gp[0][m_e][32 + j] + gp[1][m_e][32 + j] + xp[2][1];
      float orr = gp[0][m_e][48 + j] + gp[1][m_e][48 + j] + xp[3][1];
      float c = sigf(fr) * cr1 + sigf(ir) * tanhfast(gr);
      cr1 = c;
      hv[1] = sigf(orr) * tanhfast(c);
    }

    // ---- publish h: sc1 store to LLC, fire-and-forget (data IS the flag) ----
    {
      bf16x2 h2; h2.x = (bf16_t)hv[0]; h2.y = (bf16_t)hv[1];
      unsigned int u = __builtin_bit_cast(unsigned int, h2);
      unsigned int* dst = (unsigned int*)(HTR + (long long)(t + 1) * 32768 +
                                          (long long)wg * 512 + m_e * 16 + jp);
      __hip_atomic_store(dst, u, __ATOMIC_RELAXED, __HIP_MEMORY_SCOPE_AGENT);
    }
    po0 = hv[0]; po1 = hv[1];

    // ---- next-step xp prefetch (needed at next elementwise) ----
    if (t < 511) {
      const bf16_t* xpb = XP + ((long long)(t + 1) * 32 + m_e) * 4096 + wg * 16 + jp;
#pragma unroll
      for (int g = 0; g < 4; ++g) {
        bf16x2 v = *(const bf16x2*)(xpb + g * 1024);
        xp[g][0] = (float)v.x; xp[g][1] = (float)v.y;
      }
    }
  }
  // final OUT store (t = 511)
  *(float2*)(OUT + ((long long)m_e * 512 + 511) * 1024 + wg * 16 + jp) =
      make_float2(po0, po1);
}

// ---------------------------------------------------------------------------
extern "C" void kernel_launch(void* const* d_in, const int* in_sizes, int n_in,
                              void* d_out, int out_size, void* d_ws, size_t ws_size,
                              hipStream_t stream)
{
  const float* x   = (const float*)d_in[0];
  const float* h0  = (const float*)d_in[1];
  const float* c0  = (const float*)d_in[2];
  const float* Wih = (const float*)d_in[3];
  const float* Whh = (const float*)d_in[4];
  const float* bih = (const float*)d_in[5];
  const float* bhh = (const float*)d_in[6];
  float* out = (float*)d_out;

  char* ws = (char*)d_ws;
  bf16_t* xbf   = (bf16_t*)(ws + OFF_XBF);
  bf16_t* wihbf = (bf16_t*)(ws + OFF_WIH);
  bf16_t* whhbf = (bf16_t*)(ws + OFF_WHH);
  bf16_t* xproj = (bf16_t*)(ws + OFF_XPROJ);
  bf16_t* htr   = (bf16_t*)(ws + OFF_HTR);

  convert_pack<<<22560, 256, 0, stream>>>(x, h0, Wih, Whh, xbf, wihbf, whhbf, htr);
  xproj_gemm<<<dim3(128, 32), 256, 0, stream>>>(xbf, wihbf, bih, bhh, xproj);
  lstm_rec<<<64, 256, 0, stream>>>(whhbf, xproj, c0, out, htr);
}

// Round 4
// 1530.374 us; speedup vs baseline: 3.4557x; 1.1673x over previous
//
#include <hip/hip_runtime.h>

typedef __bf16 bf16_t;
typedef __bf16 bf16x8 __attribute__((ext_vector_type(8)));
typedef __bf16 bf16x4 __attribute__((ext_vector_type(4)));
typedef __bf16 bf16x2 __attribute__((ext_vector_type(2)));
typedef float f32x16 __attribute__((ext_vector_type(16)));
typedef int i32x4 __attribute__((ext_vector_type(4)));

// Problem dims: B=32, S=512, D=512, H=1024, 4H=4096
// ws layout (bytes)
#define SZ_XBF    (16384ull*512*2)      // x bf16, rows permuted to t*32+b
#define SZ_WIH    (4096ull*512*2)
#define SZ_WHH    (4096ull*1024*2)
#define SZ_XPROJ  (16384ull*4096*2)     // [t*32+b][4096] bf16
#define SZ_HTR    (513ull*32*1024*2)    // h trace bf16, slot 0 = h0
#define OFF_XBF   (0ull)
#define OFF_WIH   (OFF_XBF + SZ_XBF)
#define OFF_WHH   (OFF_WIH + SZ_WIH)
#define OFF_XPROJ (OFF_WHH + SZ_WHH)
#define OFF_HTR   (OFF_XPROJ + SZ_XPROJ)

// h trace layout (slab-contiguous per producer):
//   HTR[t*32768 + slab*512 + b*16 + col]  encodes h_t[b][slab*16 + col]
// Each (t, slab) region is 1KB contiguous, written dword-wise by exactly one
// WG. Slots 1..512 are pre-filled with canary 0xFFFFFFFF (bf16 -NaN pair,
// impossible for real h = o*tanh(c), always finite). Consumers bulk-load
// slabs with cache-bypassing loads and retry until no canary dword remains:
// the DATA is the flag. Per-dword store atomicity makes this sound fence-free.
// NEW (round 4): waves are K-QUARTERS (not ntile x khalf) -> each wave loads
// a disjoint 16KB quarter (16 slabs), computing both n-tiles for it. Zero
// intra-WG load duplication: poll traffic per retry 8MB -> 4MB chip-wide.

// ---------------------------------------------------------------------------
// Kernel 1: convert inputs to bf16 (x permuted), init h-trace slot 0,
//           canary-fill h-trace slots 1..512
// ---------------------------------------------------------------------------
__global__ __launch_bounds__(256) void convert_pack(
    const float* __restrict__ x, const float* __restrict__ h0,
    const float* __restrict__ Wih, const float* __restrict__ Whh,
    bf16_t* __restrict__ xbf, bf16_t* __restrict__ wihbf,
    bf16_t* __restrict__ whhbf, bf16_t* __restrict__ htr)
{
  long long v = (long long)blockIdx.x * 256 + threadIdx.x;
  if (v < 2097152LL) {                       // x: 8388608 floats, 4 per thread
    long long fi = v * 4;
    int b = (int)(fi >> 18);                 // 512*512 = 2^18
    int rem = (int)(fi & 0x3FFFF);
    int s = rem >> 9, d = rem & 511;
    float4 f = *(const float4*)(x + fi);
    bf16x4 o; o.x = (bf16_t)f.x; o.y = (bf16_t)f.y; o.z = (bf16_t)f.z; o.w = (bf16_t)f.w;
    *(bf16x4*)(xbf + ((long long)(s*32 + b)*512 + d)) = o;
  } else if (v < 2621440LL) {                // W_ih: 2097152 floats
    long long fi = (v - 2097152LL) * 4;
    float4 f = *(const float4*)(Wih + fi);
    bf16x4 o; o.x = (bf16_t)f.x; o.y = (bf16_t)f.y; o.z = (bf16_t)f.z; o.w = (bf16_t)f.w;
    *(bf16x4*)(wihbf + fi) = o;
  } else if (v < 3670016LL) {                // W_hh: 4194304 floats
    long long fi = (v - 2621440LL) * 4;
    float4 f = *(const float4*)(Whh + fi);
    bf16x4 o; o.x = (bf16_t)f.x; o.y = (bf16_t)f.y; o.z = (bf16_t)f.z; o.w = (bf16_t)f.w;
    *(bf16x4*)(whhbf + fi) = o;
  } else if (v < 3678208LL) {                // h0: 32768 floats -> htr slot 0 (slab layout)
    long long fi = (v - 3670016LL) * 4;
    int b = (int)(fi >> 10), c = (int)(fi & 1023);
    float4 f = *(const float4*)(h0 + fi);
    bf16x4 o; o.x = (bf16_t)f.x; o.y = (bf16_t)f.y; o.z = (bf16_t)f.z; o.w = (bf16_t)f.w;
    *(bf16x4*)(htr + (long long)(c >> 4) * 512 + b * 16 + (c & 15)) = o;
  } else if (v < 5775360LL) {                // canary fill slots 1..512 (16.78M elems)
    long long idx = v - 3678208LL;           // 2097152 threads * 8 elems
    *(int4*)(htr + 32768LL + idx * 8) = make_int4(-1, -1, -1, -1);
  }
}

// ---------------------------------------------------------------------------
// Kernel 2: x_proj = X(bf16, rows t*32+b) @ W_ih^T + b_ih + b_hh  -> bf16
// ---------------------------------------------------------------------------
__global__ __launch_bounds__(256) void xproj_gemm(
    const bf16_t* __restrict__ Xb, const bf16_t* __restrict__ Wb,
    const float* __restrict__ bih, const float* __restrict__ bhh,
    bf16_t* __restrict__ XP)
{
  __shared__ bf16_t As[128*64];
  __shared__ bf16_t Bs[128*64];
  const int tid = threadIdx.x;
  const int lane = tid & 63, wave = tid >> 6;
  const int mhalf = wave & 1, nhalf = wave >> 1;
  const int l31 = lane & 31, khi = lane >> 5;
  const int m0 = blockIdx.x * 128, n0 = blockIdx.y * 128;

  f32x16 acc[2][2] = {};

  for (int kb = 0; kb < 8; ++kb) {
    const int k0 = kb * 64;
    __syncthreads();
#pragma unroll
    for (int j = 0; j < 4; ++j) {
      int cid = j * 256 + tid;
      int r = cid >> 3, bs = cid & 7;
      int bb = bs ^ (r & 7);
      *(bf16x8*)(As + cid * 8) = *(const bf16x8*)(Xb + (long long)(m0 + r) * 512 + k0 + bb * 8);
      *(bf16x8*)(Bs + cid * 8) = *(const bf16x8*)(Wb + (long long)(n0 + r) * 512 + k0 + bb * 8);
    }
    __syncthreads();
#pragma unroll
    for (int ks = 0; ks < 4; ++ks) {
      int blk = ks * 2 + khi;
      bf16x8 af[2], bfr[2];
#pragma unroll
      for (int mt = 0; mt < 2; ++mt) {
        int r = mhalf * 64 + mt * 32 + l31;
        af[mt] = *(const bf16x8*)(As + (r * 8 + (blk ^ (r & 7))) * 8);
      }
#pragma unroll
      for (int nt = 0; nt < 2; ++nt) {
        int r = nhalf * 64 + nt * 32 + l31;
        bfr[nt] = *(const bf16x8*)(Bs + (r * 8 + (blk ^ (r & 7))) * 8);
      }
#pragma unroll
      for (int mt = 0; mt < 2; ++mt)
#pragma unroll
        for (int nt = 0; nt < 2; ++nt)
          acc[mt][nt] = __builtin_amdgcn_mfma_f32_32x32x16_bf16(af[mt], bfr[nt], acc[mt][nt], 0, 0, 0);
    }
  }
#pragma unroll
  for (int nt = 0; nt < 2; ++nt) {
    int ng = n0 + nhalf * 64 + nt * 32 + l31;
    float bias = bih[ng] + bhh[ng];
#pragma unroll
    for (int mt = 0; mt < 2; ++mt) {
#pragma unroll
      for (int r = 0; r < 16; ++r) {
        int row = (r & 3) + 8 * (r >> 2) + 4 * khi;
        long long mg = m0 + mhalf * 64 + mt * 32 + row;   // = t*32 + b
        XP[mg * 4096 + ng] = (bf16_t)(acc[mt][nt][r] + bias);
      }
    }
  }
}

// ---------------------------------------------------------------------------
// Kernel 3: persistent LSTM recurrence, canary-validated data-poll sync.
// 64 WGs x 256 threads; WG owns 16 h-cols (64 gate rows).
//  - wave = K-quarter: loads 16 disjoint slabs (16KB), computes BOTH n-tiles.
//    Poll traffic per retry round: 4MB chip-wide (was 8MB). Waves proceed
//    independently as their quarter becomes canary-free.
//  - gL now [parity][4 kq][32 m][64 n]: elementwise sums 4 partials.
//  - single barrier per step; c in regs; OUT deferred one step.
// ---------------------------------------------------------------------------
__device__ __forceinline__ float sigf(float x) { return 1.0f / (1.0f + __expf(-x)); }
__device__ __forceinline__ float tanhfast(float x) {
  float e = __expf(-2.0f * fabsf(x));
  float t = (1.0f - e) / (1.0f + e);
  return copysignf(t, x);
}
__device__ __forceinline__ unsigned umax2(unsigned a, unsigned b) { return a > b ? a : b; }
__device__ __forceinline__ unsigned umax4(i32x4 v) {
  return umax2(umax2((unsigned)v[0], (unsigned)v[1]),
               umax2((unsigned)v[2], (unsigned)v[3]));
}

#define LD16(dst, ptr, OFF) \
  asm volatile("global_load_dwordx4 %0, %1, off offset:" OFF " sc0 sc1" \
               : "=v"(dst) : "v"(ptr) : "memory")

__global__ __launch_bounds__(256, 1) void lstm_rec(
    const bf16_t* __restrict__ Whh_b, const bf16_t* __restrict__ XP,
    const float* __restrict__ c0, float* __restrict__ OUT,
    bf16_t* __restrict__ HTR)
{
  const int tid = threadIdx.x;
  const int lane = tid & 63, wave = tid >> 6;
  const int kq = wave;                              // K-quarter 0..3
  const int wg = blockIdx.x;
  const int l31 = lane & 31, khi = lane >> 5;

  // --- preload W_hh fragments for BOTH n-tiles of my K-quarter ---
  // n-tile 0: nl = l31       -> gate (l31>>4),   col (l31&15)
  // n-tile 1: nl = 32 + l31  -> gate 2+(l31>>4), col (l31&15)
  const int g0row = (l31 >> 4) * 1024 + wg * 16 + (l31 & 15);
  const int g1row = (2 + (l31 >> 4)) * 1024 + wg * 16 + (l31 & 15);
  const int kqb = kq * 256 + khi * 8;               // k-base of my quarter
  bf16x8 w0[16], w1[16];
#pragma unroll
  for (int s = 0; s < 16; ++s) {
    w0[s] = *(const bf16x8*)(Whh_b + (long long)g0row * 1024 + kqb + s * 16);
    w1[s] = *(const bf16x8*)(Whh_b + (long long)g1row * 1024 + kqb + s * 16);
  }

  // A-fragment byte base: slab (kq*16+s), row l31, cols khi*8..+8
  //   byte = t*65536 + (kq*16+s)*1024 + l31*32 + khi*16
  const char* abase = (const char*)HTR + kq * 16384 + l31 * 32 + khi * 16;

  __shared__ float gLb[2][4][32][65];   // [t parity][kq][m][n_local], padded
  const int m_e = tid >> 3;
  const int jp = (tid & 7) * 2;
  float cr0 = c0[m_e * 1024 + wg * 16 + jp];
  float cr1 = c0[m_e * 1024 + wg * 16 + jp + 1];

  // prefetch xp for t=0
  float xp[4][2];
  {
    const bf16_t* xpb = XP + (long long)m_e * 4096 + wg * 16 + jp;
#pragma unroll
    for (int g = 0; g < 4; ++g) {
      bf16x2 v = *(const bf16x2*)(xpb + g * 1024);
      xp[g][0] = (float)v.x; xp[g][1] = (float)v.y;
    }
  }

  float po0 = 0.0f, po1 = 0.0f;   // deferred OUT values (step t-1)

  for (int t = 0; t < 512; ++t) {
    // ---- bulk-load + canary-validate the 16 slabs of my K-quarter ----
    const char* p0 = abase + ((long long)t << 16);
    const char* p1 = p0 + 4096;
    const char* p2 = p0 + 8192;
    const char* p3 = p0 + 12288;
    i32x4 a[16];
    for (;;) {
      LD16(a[0],  p0, "0"); LD16(a[1],  p0, "1024"); LD16(a[2],  p0, "2048"); LD16(a[3],  p0, "3072");
      LD16(a[4],  p1, "0"); LD16(a[5],  p1, "1024"); LD16(a[6],  p1, "2048"); LD16(a[7],  p1, "3072");
      LD16(a[8],  p2, "0"); LD16(a[9],  p2, "1024"); LD16(a[10], p2, "2048"); LD16(a[11], p2, "3072");
      LD16(a[12], p3, "0"); LD16(a[13], p3, "1024"); LD16(a[14], p3, "2048"); LD16(a[15], p3, "3072");
      asm volatile("s_waitcnt vmcnt(0)" ::: "memory");
      __builtin_amdgcn_sched_barrier(0);
      unsigned mA = 0, mB = 0, mC = 0, mD = 0;
#pragma unroll
      for (int s = 0; s < 16; s += 4) {
        mA = umax2(mA, umax4(a[s]));
        mB = umax2(mB, umax4(a[s + 1]));
        mC = umax2(mC, umax4(a[s + 2]));
        mD = umax2(mD, umax4(a[s + 3]));
      }
      unsigned mx = umax2(umax2(mA, mB), umax2(mC, mD));
      if (!__any((int)(mx == 0xFFFFFFFFu))) break;
    }

    // ---- deferred OUT store for step t-1 (ack off the critical wait) ----
    if (t > 0)
      *(float2*)(OUT + ((long long)m_e * 512 + (t - 1)) * 1024 + wg * 16 + jp) =
          make_float2(po0, po1);

    // ---- gates partial for my K-quarter, both n-tiles ----
    f32x16 acc0 = {}, acc1 = {};
#pragma unroll
    for (int s = 0; s < 16; ++s) {
      bf16x8 af = __builtin_bit_cast(bf16x8, a[s]);
      acc0 = __builtin_amdgcn_mfma_f32_32x32x16_bf16(af, w0[s], acc0, 0, 0, 0);
      acc1 = __builtin_amdgcn_mfma_f32_32x32x16_bf16(af, w1[s], acc1, 0, 0, 0);
    }

    float (*gp)[65] = gLb[t & 1][kq];
#pragma unroll
    for (int r = 0; r < 16; ++r) {
      int mm = (r & 3) + 8 * (r >> 2) + 4 * khi;
      gp[mm][l31]      = acc0[r];
      gp[mm][32 + l31] = acc1[r];
    }
    __syncthreads();   // single barrier per step (gL parity-double-buffered)

    // ---- elementwise LSTM cell for (m_e, jp..jp+1), c in registers ----
    float (*ge)[32][65] = gLb[t & 1];
    float hv[2];
    {
      float ir  = ge[0][m_e][jp]      + ge[1][m_e][jp]      + ge[2][m_e][jp]      + ge[3][m_e][jp]      + xp[0][0];
      float fr  = ge[0][m_e][16 + jp] + ge[1][m_e][16 + jp] + ge[2][m_e][16 + jp] + ge[3][m_e][16 + jp] + xp[1][0];
      float gr  = ge[0][m_e][32 + jp] + ge[1][m_e][32 + jp] + ge[2][m_e][32 + jp] + ge[3][m_e][32 + jp] + xp[2][0];
      float orr = ge[0][m_e][48 + jp] + ge[1][m_e][48 + jp] + ge[2][m_e][48 + jp] + ge[3][m_e][48 + jp] + xp[3][0];
      float c = sigf(fr) * cr0 + sigf(ir) * tanhfast(gr);
      cr0 = c;
      hv[0] = sigf(orr) * tanhfast(c);
    }
    {
      int j = jp + 1;
      float ir  = ge[0][m_e][j]      + ge[1][m_e][j]      + ge[2][m_e][j]      + ge[3][m_e][j]      + xp[0][1];
      float fr  = ge[0][m_e][16 + j] + ge[1][m_e][16 + j] + ge[2][m_e][16 + j] + ge[3][m_e][16 + j] + xp[1][1];
      float gr  = ge[0][m_e][32 + j] + ge[1][m_e][32 + j] + ge[2][m_e][32 + j] + ge[3][m_e][32 + j] + xp[2][1];
      float orr = ge[0][m_e][48 + j] + ge[1][m_e][48 + j] + ge[2][m_e][48 + j] + ge[3][m_e][48 + j] + xp[3][1];
      float c = sigf(fr) * cr1 + sigf(ir) * tanhfast(gr);
      cr1 = c;
      hv[1] = sigf(orr) * tanhfast(c);
    }

    // ---- publish h: sc1 store to LLC, fire-and-forget (data IS the flag) ----
    {
      bf16x2 h2; h2.x = (bf16_t)hv[0]; h2.y = (bf16_t)hv[1];
      unsigned int u = __builtin_bit_cast(unsigned int, h2);
      unsigned int* dst = (unsigned int*)(HTR + (long long)(t + 1) * 32768 +
                                          (long long)wg * 512 + m_e * 16 + jp);
      __hip_atomic_store(dst, u, __ATOMIC_RELAXED, __HIP_MEMORY_SCOPE_AGENT);
    }
    po0 = hv[0]; po1 = hv[1];

    // ---- next-step xp prefetch (needed at next elementwise) ----
    if (t < 511) {
      const bf16_t* xpb = XP + ((long long)(t + 1) * 32 + m_e) * 4096 + wg * 16 + jp;
#pragma unroll
      for (int g = 0; g < 4; ++g) {
        bf16x2 v = *(const bf16x2*)(xpb + g * 1024);
        xp[g][0] = (float)v.x; xp[g][1] = (float)v.y;
      }
    }
  }
  // final OUT store (t = 511)
  *(float2*)(OUT + ((long long)m_e * 512 + 511) * 1024 + wg * 16 + jp) =
      make_float2(po0, po1);
}

// ---------------------------------------------------------------------------
extern "C" void kernel_launch(void* const* d_in, const int* in_sizes, int n_in,
                              void* d_out, int out_size, void* d_ws, size_t ws_size,
                              hipStream_t stream)
{
  const float* x   = (const float*)d_in[0];
  const float* h0  = (const float*)d_in[1];
  const float* c0  = (const float*)d_in[2];
  const float* Wih = (const float*)d_in[3];
  const float* Whh = (const float*)d_in[4];
  const float* bih = (const float*)d_in[5];
  const float* bhh = (const float*)d_in[6];
  float* out = (float*)d_out;

  char* ws = (char*)d_ws;
  bf16_t* xbf   = (bf16_t*)(ws + OFF_XBF);
  bf16_t* wihbf = (bf16_t*)(ws + OFF_WIH);
  bf16_t* whhbf = (bf16_t*)(ws + OFF_WHH);
  bf16_t* xproj = (bf16_t*)(ws + OFF_XPROJ);
  bf16_t* htr   = (bf16_t*)(ws + OFF_HTR);

  convert_pack<<<22560, 256, 0, stream>>>(x, h0, Wih, Whh, xbf, wihbf, whhbf, htr);
  xproj_gemm<<<dim3(128, 32), 256, 0, stream>>>(xbf, wihbf, bih, bhh, xproj);
  lstm_rec<<<64, 256, 0, stream>>>(whhbf, xproj, c0, out, htr);
}